// Round 4
// baseline (112.089 us; speedup 1.0000x reference)
//
#include <hip/hip_runtime.h>
#include <hip/hip_bf16.h>

#define LN_EPS 1e-5f
typedef __attribute__((ext_vector_type(8))) short short8v;
typedef __attribute__((ext_vector_type(4))) short short4v;
typedef __attribute__((ext_vector_type(4))) float f32x4;
typedef __hip_bfloat16 bf16;

__device__ inline float wred_sum(float v) {
#pragma unroll
  for (int off = 1; off < 64; off <<= 1) v += __shfl_xor(v, off, 64);
  return v;
}
__device__ inline float b2f(short s) {
  return __uint_as_float(((unsigned)(unsigned short)s) << 16);
}
__device__ inline short f2bs(float x) {
  union { bf16 h; short s; } u; u.h = __float2bfloat16(x); return u.s;
}
__device__ inline float rbf(float x) {  // round-trip through bf16
  return __bfloat162float(__float2bfloat16(x));
}

// ---------------- W f32 -> bf16 one-time conversion --------------------------
__global__ __launch_bounds__(256) void wcvt_kernel(
    const float* __restrict__ Wi, const float* __restrict__ Wo,
    bf16* __restrict__ Wib, bf16* __restrict__ Wob) {
  int e0 = (blockIdx.x * 256 + threadIdx.x) * 8;   // 128 blocks -> 262144 elems
  float4 a = *(const float4*)(Wi + e0);
  float4 b = *(const float4*)(Wi + e0 + 4);
  short8v t;
  t[0] = f2bs(a.x); t[1] = f2bs(a.y); t[2] = f2bs(a.z); t[3] = f2bs(a.w);
  t[4] = f2bs(b.x); t[5] = f2bs(b.y); t[6] = f2bs(b.z); t[7] = f2bs(b.w);
  *(short8v*)(Wib + e0) = t;
  a = *(const float4*)(Wo + e0);
  b = *(const float4*)(Wo + e0 + 4);
  t[0] = f2bs(a.x); t[1] = f2bs(a.y); t[2] = f2bs(a.z); t[3] = f2bs(a.w);
  t[4] = f2bs(b.x); t[5] = f2bs(b.y); t[6] = f2bs(b.z); t[7] = f2bs(b.w);
  *(short8v*)(Wob + e0) = t;
}

// ---------------- 64x512 GEMM vs W^T, A fetched once -------------------------
// MODE 0: A=f32 {q,k,v} + fused LN in, full per-tensor epilogue out (bf16).
// MODE 1: A=bf16 attnb, C=f32 out + bias.
template<int MODE>
__global__ __launch_bounds__(256) void mm512_kernel(
    const float* __restrict__ q, const float* __restrict__ k,
    const float* __restrict__ v, const bf16* __restrict__ Ab,
    const bf16* __restrict__ Wb,
    const float* __restrict__ g, const float* __restrict__ bln,
    const float* __restrict__ bias,
    bf16* __restrict__ f_q, bf16* __restrict__ fkt, bf16* __restrict__ fkh,
    bf16* __restrict__ fvt,
    float* __restrict__ rn, float* __restrict__ mn, float* __restrict__ vr,
    float* __restrict__ gp, float* __restrict__ out) {
  __shared__ bf16 As[64 * 68];
  __shared__ bf16 Bs[512 * 68];
  __shared__ float lmS[64], lrS[64];
  int tid = threadIdx.x;
  int bi = blockIdx.x;
  int tensor = 0, rb = bi;
  const float* A = nullptr;
  if (MODE == 0) {
    tensor = bi >> 6; rb = bi & 63;
    A = tensor == 0 ? q : (tensor == 1 ? k : v);
  }
  int row0 = rb * 64;
  int wv = tid >> 6, l = tid & 63, fr = l & 15, lq = l >> 4;
  int srow = tid >> 2, skc = (tid & 3) * 16;

  if (MODE == 0) {
    // pass 0: LN row stats (row tile is L2-resident for the main loop)
    const float4* p = (const float4*)(A + (size_t)(row0 + srow) * 512 + (tid & 3) * 128);
    float s = 0.f, ss = 0.f;
#pragma unroll 8
    for (int i = 0; i < 32; ++i) {
      float4 a = p[i];
      s += a.x + a.y + a.z + a.w;
      ss += a.x*a.x + a.y*a.y + a.z*a.z + a.w*a.w;
    }
    s += __shfl_xor(s, 1, 64);  s += __shfl_xor(s, 2, 64);
    ss += __shfl_xor(ss, 1, 64); ss += __shfl_xor(ss, 2, 64);
    if ((tid & 3) == 0) {
      float m = s * (1.f / 512.f);
      lmS[srow] = m;
      lrS[srow] = rsqrtf(ss * (1.f / 512.f) - m * m + LN_EPS);
    }
    __syncthreads();
  }

  f32x4 acc[4][8];
#pragma unroll
  for (int fi = 0; fi < 4; ++fi)
#pragma unroll
    for (int j = 0; j < 8; ++j)
#pragma unroll
      for (int e = 0; e < 4; ++e) acc[fi][j][e] = 0.f;

  for (int ks = 0; ks < 512; ks += 64) {
    if (MODE == 0) {
      float m = lmS[srow], r = lrS[srow];
#pragma unroll
      for (int qq = 0; qq < 4; ++qq) {
        float4 a  = *(const float4*)(A + (size_t)(row0 + srow) * 512 + ks + skc + qq * 4);
        float4 gg = *(const float4*)(g + ks + skc + qq * 4);
        float4 bb = *(const float4*)(bln + ks + skc + qq * 4);
        short4v t;
        t[0] = f2bs((a.x - m) * r * gg.x + bb.x);
        t[1] = f2bs((a.y - m) * r * gg.y + bb.y);
        t[2] = f2bs((a.z - m) * r * gg.z + bb.z);
        t[3] = f2bs((a.w - m) * r * gg.w + bb.w);
        *(short4v*)&As[srow * 68 + skc + qq * 4] = t;
      }
    } else {
      const bf16* src = Ab + (size_t)(row0 + srow) * 512 + ks + skc;
      *(short8v*)&As[srow * 68 + skc]     = *(const short8v*)src;
      *(short8v*)&As[srow * 68 + skc + 8] = *(const short8v*)(src + 8);
    }
    {
      int cr = tid >> 2, kcb = (tid & 3) * 16;
#pragma unroll
      for (int it = 0; it < 8; ++it) {
        int colr = cr + it * 64;
        const bf16* src = Wb + (size_t)colr * 512 + ks + kcb;
        *(short8v*)&Bs[colr * 68 + kcb]     = *(const short8v*)src;
        *(short8v*)&Bs[colr * 68 + kcb + 8] = *(const short8v*)(src + 8);
      }
    }
    __syncthreads();
#pragma unroll
    for (int kk = 0; kk < 64; kk += 32) {
      short8v a_[4];
#pragma unroll
      for (int fi = 0; fi < 4; ++fi)
        a_[fi] = *(const short8v*)&As[(fi * 16 + fr) * 68 + kk + lq * 8];
#pragma unroll
      for (int j = 0; j < 8; ++j) {
        short8v bv = *(const short8v*)&Bs[(wv * 128 + j * 16 + fr) * 68 + kk + lq * 8];
#pragma unroll
        for (int fi = 0; fi < 4; ++fi)
          acc[fi][j] = __builtin_amdgcn_mfma_f32_16x16x32_bf16(a_[fi], bv, acc[fi][j], 0, 0, 0);
      }
    }
    __syncthreads();
  }

  if (MODE == 1) {
#pragma unroll
    for (int j = 0; j < 8; ++j) {
      int col = wv * 128 + j * 16 + fr;
      float bvv = bias[col];
#pragma unroll
      for (int fi = 0; fi < 4; ++fi)
#pragma unroll
        for (int rr = 0; rr < 4; ++rr)
          out[(size_t)(row0 + fi * 16 + lq * 4 + rr) * 512 + col] = acc[fi][j][rr] + bvv;
    }
    return;
  }
  // ---- MODE 0 epilogue ----
  int b = rb >> 4, n0 = (rb & 15) * 64;
  if (tensor == 2) {
#pragma unroll
    for (int hh = 0; hh < 2; ++hh) {
      int h = wv * 2 + hh, hb = h * 4 + b;
#pragma unroll
      for (int jj = 0; jj < 4; ++jj) {
        int dv = jj * 16 + fr;
#pragma unroll
        for (int fi = 0; fi < 4; ++fi) {
          short4v t;
#pragma unroll
          for (int rr = 0; rr < 4; ++rr) t[rr] = f2bs(acc[fi][hh * 4 + jj][rr]);
          *(short4v*)(fvt + (size_t)(hb * 64 + dv) * 1024 + n0 + fi * 16 + lq * 4) = t;
        }
      }
    }
    return;
  }
#pragma unroll
  for (int hh = 0; hh < 2; ++hh) {
    int h = wv * 2 + hh, hb = h * 4 + b;
    float sr[4][4], sq2[4][4];
#pragma unroll
    for (int fi = 0; fi < 4; ++fi)
#pragma unroll
      for (int rr = 0; rr < 4; ++rr) {
        float s = 0.f, ss = 0.f;
#pragma unroll
        for (int jj = 0; jj < 4; ++jj) {
          float x = rbf(acc[fi][hh * 4 + jj][rr]);
          s += x; ss += x * x;
        }
#pragma unroll
        for (int off = 1; off < 16; off <<= 1) {
          s += __shfl_xor(s, off, 64);
          ss += __shfl_xor(ss, off, 64);
        }
        sr[fi][rr] = s; sq2[fi][rr] = ss;
      }
    if (tensor == 0) {
#pragma unroll
      for (int jj = 0; jj < 4; ++jj) {
        int d = jj * 16 + fr;
#pragma unroll
        for (int fi = 0; fi < 4; ++fi)
#pragma unroll
          for (int rr = 0; rr < 4; ++rr)
            f_q[(size_t)(b * 1024 + n0 + fi * 16 + lq * 4 + rr) * 512 + h * 64 + d] =
                __float2bfloat16(acc[fi][hh * 4 + jj][rr]);
      }
      if (fr == 0)
#pragma unroll
        for (int fi = 0; fi < 4; ++fi)
#pragma unroll
          for (int rr = 0; rr < 4; ++rr) {
            int nn = n0 + fi * 16 + lq * 4 + rr;
            size_t idx = (size_t)hb * 1024 + nn;
            float mean = sr[fi][rr] * (1.f / 64.f);
            rn[idx] = rsqrtf(sq2[fi][rr]);
            mn[idx] = mean;
            vr[idx] = (sq2[fi][rr] - 64.f * mean * mean) * (1.f / 63.f);
          }
    } else {
#pragma unroll
      for (int fi = 0; fi < 4; ++fi) {
        float rnv[4];
#pragma unroll
        for (int rr = 0; rr < 4; ++rr) rnv[rr] = rsqrtf(sq2[fi][rr]);
#pragma unroll
        for (int jj = 0; jj < 4; ++jj) {
          short4v tp, th;
#pragma unroll
          for (int rr = 0; rr < 4; ++rr) {
            float x = acc[fi][hh * 4 + jj][rr];
            tp[rr] = f2bs(x);
            th[rr] = f2bs(rbf(x) * rnv[rr]);
          }
          size_t off = (size_t)(hb * 64 + jj * 16 + fr) * 1024 + n0 + fi * 16 + lq * 4;
          *(short4v*)(fkt + off) = tp;
          *(short4v*)(fkh + off) = th;
        }
        if (fr == 0)
#pragma unroll
          for (int rr = 0; rr < 4; ++rr) {
            int nn = n0 + fi * 16 + lq * 4 + rr;
            size_t idx = 32768 + (size_t)hb * 1024 + nn;
            float mean = sr[fi][rr] * (1.f / 64.f);
            mn[idx] = mean;
            vr[idx] = (sq2[fi][rr] - 64.f * mean * mean) * (1.f / 63.f);
          }
      }
    }
  }
  // global-mean column partials (q, k only)
#pragma unroll
  for (int j = 0; j < 8; ++j) {
    float c = 0.f;
#pragma unroll
    for (int fi = 0; fi < 4; ++fi)
#pragma unroll
      for (int rr = 0; rr < 4; ++rr) c += rbf(acc[fi][j][rr]);
    c += __shfl_xor(c, 16, 64);
    c += __shfl_xor(c, 32, 64);
    if (lq == 0)
      gp[(size_t)(tensor * 64 + rb) * 512 + wv * 128 + j * 16 + fr] = c;
  }
}

// ---------------- aux: full KtV -> A_T | rank1 | mlp -------------------------
__global__ __launch_bounds__(256) void aux_kernel(
    const bf16* __restrict__ fvt, const bf16* __restrict__ fkt,
    const bf16* __restrict__ fkh,
    const float* __restrict__ mn, const float* __restrict__ vr,
    const float* __restrict__ gp,
    const float* __restrict__ W1, const float* __restrict__ b1,
    const float* __restrict__ lg, const float* __restrict__ lb,
    const float* __restrict__ W2, const float* __restrict__ b2,
    bf16* __restrict__ A_T, float* __restrict__ kvm, float* __restrict__ kvv,
    float* __restrict__ wts) {
  __shared__ float sh[2560];
  int bid = blockIdx.x, tid = threadIdx.x;
  int wv = tid >> 6, l = tid & 63, fr = l & 15, lq = l >> 4;
  if (bid < 32) {
    // ---- A_pl[dv][dk]=sum_m V[m][dv]*K[m][dk]; A_ht with khat; K=1024 ----
    int hb = bid;
    f32x4 apl[4], aht[4];
#pragma unroll
    for (int j = 0; j < 4; ++j)
#pragma unroll
      for (int e = 0; e < 4; ++e) { apl[j][e] = 0.f; aht[j][e] = 0.f; }
    size_t arow = (size_t)(hb * 64 + wv * 16 + fr) * 1024;
#pragma unroll 4
    for (int m0 = 0; m0 < 1024; m0 += 32) {
      short8v av = *(const short8v*)(fvt + arow + m0 + lq * 8);
#pragma unroll
      for (int j = 0; j < 4; ++j) {
        size_t brow = (size_t)(hb * 64 + j * 16 + fr) * 1024 + m0 + lq * 8;
        short8v bp = *(const short8v*)(fkt + brow);
        short8v bh = *(const short8v*)(fkh + brow);
        apl[j] = __builtin_amdgcn_mfma_f32_16x16x32_bf16(av, bp, apl[j], 0, 0, 0);
        aht[j] = __builtin_amdgcn_mfma_f32_16x16x32_bf16(av, bh, aht[j], 0, 0, 0);
      }
    }
#pragma unroll
    for (int j = 0; j < 4; ++j)
#pragma unroll
      for (int rr = 0; rr < 4; ++rr) {
        int dv = wv * 16 + lq * 4 + rr, dk = j * 16 + fr;
        A_T[(size_t)hb * 8192 + dv * 64 + dk] = __float2bfloat16(apl[j][rr]);
        A_T[(size_t)hb * 8192 + 4096 + dv * 64 + dk] = __float2bfloat16(aht[j][rr]);
      }
  } else if (bid < 64) {
    // ---- rank1 ----
    int hb = bid - 32;
    float* kmL = sh; float* kvL = sh + 1024; float* red = sh + 2048;
    for (int i = tid; i < 1024; i += 256) {
      kmL[i] = mn[32768 + hb * 1024 + i];
      kvL[i] = vr[32768 + hb * 1024 + i];
    }
    __syncthreads();
    int dv = tid >> 2, seg = tid & 3;
    float am = 0.f, av = 0.f;
    size_t rowb = (size_t)(hb * 64 + dv) * 1024 + seg * 256;
    for (int i = 0; i < 256; i += 8) {
      short8v vv = *(const short8v*)(fvt + rowb + i);
#pragma unroll
      for (int e = 0; e < 8; ++e) {
        float f = b2f(vv[e]);
        am += kmL[seg * 256 + i + e] * f;
        av += kvL[seg * 256 + i + e] * f;
      }
    }
    red[dv * 4 + seg] = am;
    red[256 + dv * 4 + seg] = av;
    __syncthreads();
    if (tid < 64) {
      kvm[hb * 64 + tid] = red[tid * 4] + red[tid * 4 + 1] + red[tid * 4 + 2] + red[tid * 4 + 3];
      kvv[hb * 64 + tid] = red[256 + tid * 4] + red[256 + tid * 4 + 1] +
                           red[256 + tid * 4 + 2] + red[256 + tid * 4 + 3];
    }
  } else {
    // ---- head-weight MLP ----
    float* fqv = sh; float* fkv = sh + 512;
    for (int c = tid; c < 512; c += 256) {
      float sq = 0.f, sk = 0.f;
      for (int p = 0; p < 64; ++p) {
        sq += gp[(size_t)p * 512 + c];
        sk += gp[(size_t)(64 + p) * 512 + c];
      }
      fqv[c] = sq * (1.f / 4096.f);
      fkv[c] = sk * (1.f / 4096.f);
    }
    __syncthreads();
#pragma unroll
    for (int hh = 0; hh < 2; ++hh) {
      int h = hh * 4 + wv, j = l;
      float pre = b1[j];
      for (int i = 0; i < 64; ++i) pre += fqv[h * 64 + i] * W1[j * 128 + i];
      for (int i = 0; i < 64; ++i) pre += fkv[h * 64 + i] * W1[j * 128 + 64 + i];
      float s = wred_sum(pre);
      float ss = wred_sum(pre * pre);
      float mean = s * (1.f / 64.f);
      float var = ss * (1.f / 64.f) - mean * mean;
      float hdn = (pre - mean) * rsqrtf(var + LN_EPS) * lg[j] + lb[j];
      hdn = fmaxf(hdn, 0.f);
      float l0 = wred_sum(hdn * W2[0 * 64 + j]) + b2[0];
      float l1 = wred_sum(hdn * W2[1 * 64 + j]) + b2[1];
      float l2 = wred_sum(hdn * W2[2 * 64 + j]) + b2[2];
      float mx = fmaxf(l0, fmaxf(l1, l2));
      float e0 = __expf(l0 - mx), e1 = __expf(l1 - mx), e2 = __expf(l2 - mx);
      float inv = 1.f / (e0 + e1 + e2);
      if (j == 0) {
        wts[h * 3 + 0] = e0 * inv;
        wts[h * 3 + 1] = e1 * inv;
        wts[h * 3 + 2] = e2 * inv;
      }
    }
  }
}

// ---------------- apply: out = w0*qrn*(Q@Ahat^T) + f1*(Q@Apl^T) + rank1 ------
__global__ __launch_bounds__(256) void apply_kernel(
    const bf16* __restrict__ f_q, const bf16* __restrict__ A_T,
    const float* __restrict__ rn, const float* __restrict__ mn,
    const float* __restrict__ vr, const float* __restrict__ wts,
    const float* __restrict__ kvm, const float* __restrict__ kvv,
    bf16* __restrict__ attnb) {
  __shared__ bf16 Qs[64 * 72];
  __shared__ bf16 Ap[64 * 72];
  __shared__ bf16 Ah[64 * 72];
  __shared__ float qrnL[64], qmnL[64], qvrL[64], kvmL[64], kvvL[64];
  int qt = blockIdx.x, hbid = blockIdx.y;
  int h = hbid >> 2, b = hbid & 3;
  int tid = threadIdx.x;
  int wv = tid >> 6, l = tid & 63, fr = l & 15, lq = l >> 4;
  {
    int row = tid >> 2, qq = (tid & 3) * 16;
    const bf16* qsrc = f_q + (size_t)(b * 1024 + qt * 64 + row) * 512 + h * 64 + qq;
    *(short8v*)&Qs[row * 72 + qq] = *(const short8v*)qsrc;
    *(short8v*)&Qs[row * 72 + qq + 8] = *(const short8v*)(qsrc + 8);
    const bf16* asrc = A_T + (size_t)hbid * 8192 + row * 64 + qq;
    *(short8v*)&Ap[row * 72 + qq] = *(const short8v*)asrc;
    *(short8v*)&Ap[row * 72 + qq + 8] = *(const short8v*)(asrc + 8);
    *(short8v*)&Ah[row * 72 + qq] = *(const short8v*)(asrc + 4096);
    *(short8v*)&Ah[row * 72 + qq + 8] = *(const short8v*)(asrc + 4096 + 8);
  }
  if (tid < 64) {
    qrnL[tid] = rn[(size_t)hbid * 1024 + qt * 64 + tid];
    qmnL[tid] = mn[(size_t)hbid * 1024 + qt * 64 + tid];
    qvrL[tid] = vr[(size_t)hbid * 1024 + qt * 64 + tid];
    kvmL[tid] = kvm[hbid * 64 + tid];
    kvvL[tid] = kvv[hbid * 64 + tid];
  }
  __syncthreads();
  f32x4 ap_[4], ah_[4];
#pragma unroll
  for (int j = 0; j < 4; ++j)
#pragma unroll
    for (int e = 0; e < 4; ++e) { ap_[j][e] = 0.f; ah_[j][e] = 0.f; }
#pragma unroll
  for (int kk = 0; kk < 64; kk += 32) {
    short8v aq = *(const short8v*)&Qs[(wv * 16 + fr) * 72 + kk + lq * 8];
#pragma unroll
    for (int j = 0; j < 4; ++j) {
      short8v bp = *(const short8v*)&Ap[(j * 16 + fr) * 72 + kk + lq * 8];
      short8v bh = *(const short8v*)&Ah[(j * 16 + fr) * 72 + kk + lq * 8];
      ap_[j] = __builtin_amdgcn_mfma_f32_16x16x32_bf16(aq, bp, ap_[j], 0, 0, 0);
      ah_[j] = __builtin_amdgcn_mfma_f32_16x16x32_bf16(aq, bh, ah_[j], 0, 0, 0);
    }
  }
  float w0 = wts[h * 3 + 0], w1 = wts[h * 3 + 1], w2 = wts[h * 3 + 2];
  float f1 = w1 * (1.f / 64.f), w264 = w2 * (1.f / 64.f);
#pragma unroll
  for (int j = 0; j < 4; ++j) {
    int dv = j * 16 + fr;
    float km = kvmL[dv], kv2 = kvvL[dv];
#pragma unroll
    for (int rr = 0; rr < 4; ++rr) {
      int n = wv * 16 + lq * 4 + rr;
      float o = w0 * qrnL[n] * ah_[j][rr] + f1 * ap_[j][rr]
              - w1 * qmnL[n] * km + w264 * qvrL[n] * kv2;
      attnb[(size_t)(b * 1024 + qt * 64 + n) * 512 + h * 64 + dv] = __float2bfloat16(o);
    }
  }
}

extern "C" void kernel_launch(void* const* d_in, const int* in_sizes, int n_in,
                              void* d_out, int out_size, void* d_ws, size_t ws_size,
                              hipStream_t stream) {
  const float* q     = (const float*)d_in[0];
  const float* k     = (const float*)d_in[1];
  const float* v     = (const float*)d_in[2];
  const float* ln_g  = (const float*)d_in[3];
  const float* ln_b  = (const float*)d_in[4];
  const float* W_in  = (const float*)d_in[5];
  const float* W_out = (const float*)d_in[6];
  const float* b_out = (const float*)d_in[7];
  const float* wp_W1 = (const float*)d_in[8];
  const float* wp_b1 = (const float*)d_in[9];
  const float* wp_lg = (const float*)d_in[10];
  const float* wp_lb = (const float*)d_in[11];
  const float* wp_W2 = (const float*)d_in[12];
  const float* wp_b2 = (const float*)d_in[13];
  float* out = (float*)d_out;

  char* w8 = (char*)d_ws;
  bf16* f_q   = (bf16*)(w8);                             // 4 MB
  bf16* fkt   = (bf16*)(w8 + (4u << 20));                // 4 MB
  bf16* fkh   = (bf16*)(w8 + (8u << 20));                // 4 MB
  bf16* fvt   = (bf16*)(w8 + (12u << 20));               // 4 MB
  bf16* attnb = (bf16*)(w8 + (16u << 20));               // 4 MB
  bf16* A_T   = (bf16*)(w8 + (20u << 20));               // 512 KB
  bf16* Wib   = (bf16*)(w8 + (20u << 20) + (512u << 10)); // 512 KB
  bf16* Wob   = (bf16*)(w8 + (21u << 20));               // 512 KB
  float* fb   = (float*)(w8 + (21u << 20) + (512u << 10));
  float* rn  = fb;            // 32768
  float* mn  = fb + 32768;    // 65536 (q, k)
  float* vr  = fb + 98304;    // 65536
  float* gp  = fb + 163840;   // 65536 ([2*64][512])
  float* kvm = fb + 229376;   // 2048
  float* kvv = fb + 231424;   // 2048
  float* wts = fb + 233472;   // 24

  wcvt_kernel<<<128, 256, 0, stream>>>(W_in, W_out, Wib, Wob);
  mm512_kernel<0><<<192, 256, 0, stream>>>(
      q, k, v, nullptr, Wib, ln_g, ln_b, nullptr,
      f_q, fkt, fkh, fvt, rn, mn, vr, gp, nullptr);
  aux_kernel<<<65, 256, 0, stream>>>(
      fvt, fkt, fkh, mn, vr, gp, wp_W1, wp_b1, wp_lg, wp_lb, wp_W2, wp_b2,
      A_T, kvm, kvv, wts);
  apply_kernel<<<dim3(16, 32), 256, 0, stream>>>(
      f_q, A_T, rn, mn, vr, wts, kvm, kvv, attnb);
  mm512_kernel<1><<<64, 256, 0, stream>>>(
      nullptr, nullptr, nullptr, attnb, Wob, nullptr, nullptr, b_out,
      nullptr, nullptr, nullptr, nullptr, nullptr, nullptr, nullptr, nullptr, out);
}

// Round 5
// 85.630 us; speedup vs baseline: 1.3090x; 1.3090x over previous
//
#include <hip/hip_runtime.h>
#include <hip/hip_bf16.h>

#define LN_EPS 1e-5f
typedef __attribute__((ext_vector_type(8))) short short8v;
typedef __attribute__((ext_vector_type(4))) short short4v;
typedef __attribute__((ext_vector_type(4))) float f32x4;
typedef __hip_bfloat16 bf16;

__device__ inline float wred_sum(float v) {
#pragma unroll
  for (int off = 1; off < 64; off <<= 1) v += __shfl_xor(v, off, 64);
  return v;
}
__device__ inline float b2f(short s) {
  return __uint_as_float(((unsigned)(unsigned short)s) << 16);
}
__device__ inline short f2bs(float x) {
  union { bf16 h; short s; } u; u.h = __float2bfloat16(x); return u.s;
}
__device__ inline float rbf(float x) {
  return __bfloat162float(__float2bfloat16(x));
}

// ---- fused: LN(q,k,v) -> bf16 rows  |  W_in/W_out f32 -> bf16 ---------------
__global__ __launch_bounds__(256) void lncvt_kernel(
    const float* __restrict__ q, const float* __restrict__ k,
    const float* __restrict__ v,
    const float* __restrict__ g, const float* __restrict__ bln,
    const float* __restrict__ Wi, const float* __restrict__ Wo,
    bf16* __restrict__ abf, bf16* __restrict__ Wib, bf16* __restrict__ Wob) {
  int bid = blockIdx.x, tid = threadIdx.x;
  if (bid < 3072) {
    int wave = tid >> 6, lane = tid & 63;
    int grow = bid * 4 + wave;                // 0..12287
    int tensor = grow >> 12, row = grow & 4095;
    const float* src = tensor == 0 ? q : (tensor == 1 ? k : v);
    const float4* p = (const float4*)(src + (size_t)row * 512 + lane * 8);
    float4 a = p[0], b = p[1];
    float s  = a.x + a.y + a.z + a.w + b.x + b.y + b.z + b.w;
    float ss = a.x*a.x + a.y*a.y + a.z*a.z + a.w*a.w
             + b.x*b.x + b.y*b.y + b.z*b.z + b.w*b.w;
    s = wred_sum(s);
    ss = wred_sum(ss);
    float m = s * (1.f / 512.f);
    float r = rsqrtf(ss * (1.f / 512.f) - m * m + LN_EPS);
    float4 g0 = *(const float4*)(g + lane * 8);
    float4 g1 = *(const float4*)(g + lane * 8 + 4);
    float4 b0 = *(const float4*)(bln + lane * 8);
    float4 b1 = *(const float4*)(bln + lane * 8 + 4);
    short8v t;
    t[0] = f2bs((a.x - m) * r * g0.x + b0.x);
    t[1] = f2bs((a.y - m) * r * g0.y + b0.y);
    t[2] = f2bs((a.z - m) * r * g0.z + b0.z);
    t[3] = f2bs((a.w - m) * r * g0.w + b0.w);
    t[4] = f2bs((b.x - m) * r * g1.x + b1.x);
    t[5] = f2bs((b.y - m) * r * g1.y + b1.y);
    t[6] = f2bs((b.z - m) * r * g1.z + b1.z);
    t[7] = f2bs((b.w - m) * r * g1.w + b1.w);
    *(short8v*)(abf + (size_t)grow * 512 + lane * 8) = t;
  } else {
    int e0 = ((bid - 3072) * 256 + tid) * 8;  // 128 blocks cover 262144 elems
    float4 a = *(const float4*)(Wi + e0);
    float4 b = *(const float4*)(Wi + e0 + 4);
    short8v t;
    t[0] = f2bs(a.x); t[1] = f2bs(a.y); t[2] = f2bs(a.z); t[3] = f2bs(a.w);
    t[4] = f2bs(b.x); t[5] = f2bs(b.y); t[6] = f2bs(b.z); t[7] = f2bs(b.w);
    *(short8v*)(Wib + e0) = t;
    a = *(const float4*)(Wo + e0);
    b = *(const float4*)(Wo + e0 + 4);
    t[0] = f2bs(a.x); t[1] = f2bs(a.y); t[2] = f2bs(a.z); t[3] = f2bs(a.w);
    t[4] = f2bs(b.x); t[5] = f2bs(b.y); t[6] = f2bs(b.z); t[7] = f2bs(b.w);
    *(short8v*)(Wob + e0) = t;
  }
}

// ---- 64x128-tile GEMM vs W^T. MODE 0: proj + epilogue. MODE 1: outproj. ----
template<int MODE>
__global__ __launch_bounds__(256) void mm_kernel(
    const bf16* __restrict__ Asrc, const bf16* __restrict__ Wb,
    const float* __restrict__ bias,
    bf16* __restrict__ f_q, bf16* __restrict__ fkt, bf16* __restrict__ fkh,
    bf16* __restrict__ fvt,
    float* __restrict__ rn, float* __restrict__ mn, float* __restrict__ vr,
    float* __restrict__ gp, float* __restrict__ out) {
  __shared__ bf16 As[64 * 72];
  __shared__ bf16 Bs[128 * 72];
  __shared__ float gpbuf[4][128];
  int tid = threadIdx.x;
  int bj = blockIdx.x, bi = blockIdx.y;
  int row0 = bi * 64;
  int wv = tid >> 6, l = tid & 63, fr = l & 15, lq = l >> 4;
  int sarow = tid >> 2, sakc = (tid & 3) * 16;     // A staging
  int sbrow = tid >> 1, sbkc = (tid & 1) * 32;     // B staging
  f32x4 acc[8];
#pragma unroll
  for (int j = 0; j < 8; ++j)
#pragma unroll
    for (int e = 0; e < 4; ++e) acc[j][e] = 0.f;

  for (int ks = 0; ks < 512; ks += 64) {
    {
      const bf16* src = Asrc + (size_t)(row0 + sarow) * 512 + ks + sakc;
      *(short8v*)&As[sarow * 72 + sakc]     = *(const short8v*)src;
      *(short8v*)&As[sarow * 72 + sakc + 8] = *(const short8v*)(src + 8);
    }
    {
      const bf16* src = Wb + (size_t)(bj * 128 + sbrow) * 512 + ks + sbkc;
#pragma unroll
      for (int c = 0; c < 4; ++c)
        *(short8v*)&Bs[sbrow * 72 + sbkc + c * 8] = *(const short8v*)(src + c * 8);
    }
    __syncthreads();
#pragma unroll
    for (int kk = 0; kk < 64; kk += 32) {
      short8v af = *(const short8v*)&As[(wv * 16 + fr) * 72 + kk + lq * 8];
#pragma unroll
      for (int j = 0; j < 8; ++j) {
        short8v bv = *(const short8v*)&Bs[(j * 16 + fr) * 72 + kk + lq * 8];
        acc[j] = __builtin_amdgcn_mfma_f32_16x16x32_bf16(af, bv, acc[j], 0, 0, 0);
      }
    }
    __syncthreads();
  }

  if (MODE == 1) {
#pragma unroll
    for (int j = 0; j < 8; ++j) {
      int col = bj * 128 + j * 16 + fr;
      float bvv = bias[col];
#pragma unroll
      for (int rr = 0; rr < 4; ++rr)
        out[(size_t)(row0 + wv * 16 + lq * 4 + rr) * 512 + col] = acc[j][rr] + bvv;
    }
    return;
  }

  // ---- MODE 0 epilogue ----
  int tensor = bi >> 6, rb = bi & 63;
  int b = rb >> 4, n0 = (rb & 15) * 64;
  int nbase = n0 + wv * 16 + lq * 4;          // +rr
  if (tensor == 2) {
#pragma unroll
    for (int j = 0; j < 8; ++j) {
      int h = bj * 2 + (j >> 2), hb = h * 4 + b;
      int dv = (j & 3) * 16 + fr;
      short4v t;
#pragma unroll
      for (int rr = 0; rr < 4; ++rr) t[rr] = f2bs(acc[j][rr]);
      *(short4v*)(fvt + (size_t)(hb * 64 + dv) * 1024 + nbase) = t;
    }
    return;
  }
  float vb[8][4];
#pragma unroll
  for (int j = 0; j < 8; ++j)
#pragma unroll
    for (int rr = 0; rr < 4; ++rr) vb[j][rr] = rbf(acc[j][rr]);

#pragma unroll
  for (int hh = 0; hh < 2; ++hh) {
    int h = bj * 2 + hh, hb = h * 4 + b;
    float sr[4], s2[4];
#pragma unroll
    for (int rr = 0; rr < 4; ++rr) {
      float s = 0.f, ss = 0.f;
#pragma unroll
      for (int jj = 0; jj < 4; ++jj) {
        float x = vb[hh * 4 + jj][rr];
        s += x; ss += x * x;
      }
#pragma unroll
      for (int off = 1; off < 16; off <<= 1) {
        s += __shfl_xor(s, off, 64);
        ss += __shfl_xor(ss, off, 64);
      }
      sr[rr] = s; s2[rr] = ss;
    }
    if (tensor == 0) {
#pragma unroll
      for (int jj = 0; jj < 4; ++jj) {
        int d = jj * 16 + fr;
#pragma unroll
        for (int rr = 0; rr < 4; ++rr)
          f_q[(size_t)(b * 1024 + nbase + rr) * 512 + h * 64 + d] =
              __float2bfloat16(acc[hh * 4 + jj][rr]);
      }
      if (fr == 0)
#pragma unroll
        for (int rr = 0; rr < 4; ++rr) {
          size_t idx = (size_t)hb * 1024 + nbase + rr;
          float mean = sr[rr] * (1.f / 64.f);
          rn[idx] = rsqrtf(s2[rr]);
          mn[idx] = mean;
          vr[idx] = (s2[rr] - 64.f * mean * mean) * (1.f / 63.f);
        }
    } else {
      float rnv[4];
#pragma unroll
      for (int rr = 0; rr < 4; ++rr) rnv[rr] = rsqrtf(s2[rr]);
#pragma unroll
      for (int jj = 0; jj < 4; ++jj) {
        int dk = jj * 16 + fr;
        short4v tp, th;
#pragma unroll
        for (int rr = 0; rr < 4; ++rr) {
          tp[rr] = f2bs(acc[hh * 4 + jj][rr]);
          th[rr] = f2bs(vb[hh * 4 + jj][rr] * rnv[rr]);
        }
        size_t off = (size_t)(hb * 64 + dk) * 1024 + nbase;
        *(short4v*)(fkt + off) = tp;
        *(short4v*)(fkh + off) = th;
      }
      if (fr == 0)
#pragma unroll
        for (int rr = 0; rr < 4; ++rr) {
          size_t idx = 32768 + (size_t)hb * 1024 + nbase + rr;
          float mean = sr[rr] * (1.f / 64.f);
          mn[idx] = mean;
          vr[idx] = (s2[rr] - 64.f * mean * mean) * (1.f / 63.f);
        }
    }
  }
  // global-mean column partials
#pragma unroll
  for (int j = 0; j < 8; ++j) {
    float c = 0.f;
#pragma unroll
    for (int rr = 0; rr < 4; ++rr) c += vb[j][rr];
    c += __shfl_xor(c, 16, 64);
    c += __shfl_xor(c, 32, 64);
    if (lq == 0) gpbuf[wv][j * 16 + fr] = c;
  }
  __syncthreads();
  if (tid < 128)
    gp[(size_t)(tensor * 64 + rb) * 512 + bj * 128 + tid] =
        gpbuf[0][tid] + gpbuf[1][tid] + gpbuf[2][tid] + gpbuf[3][tid];
}

// ---------------- aux: full KtV -> A_T | rank1 | mlp -------------------------
__global__ __launch_bounds__(256) void aux_kernel(
    const bf16* __restrict__ fvt, const bf16* __restrict__ fkt,
    const bf16* __restrict__ fkh,
    const float* __restrict__ mn, const float* __restrict__ vr,
    const float* __restrict__ gp,
    const float* __restrict__ W1, const float* __restrict__ b1,
    const float* __restrict__ lg, const float* __restrict__ lb,
    const float* __restrict__ W2, const float* __restrict__ b2,
    bf16* __restrict__ A_T, float* __restrict__ kvm, float* __restrict__ kvv,
    float* __restrict__ wts) {
  __shared__ float sh[2560];
  int bid = blockIdx.x, tid = threadIdx.x;
  int wv = tid >> 6, l = tid & 63, fr = l & 15, lq = l >> 4;
  if (bid < 32) {
    int hb = bid;
    f32x4 apl[4], aht[4];
#pragma unroll
    for (int j = 0; j < 4; ++j)
#pragma unroll
      for (int e = 0; e < 4; ++e) { apl[j][e] = 0.f; aht[j][e] = 0.f; }
    size_t arow = (size_t)(hb * 64 + wv * 16 + fr) * 1024;
#pragma unroll 4
    for (int m0 = 0; m0 < 1024; m0 += 32) {
      short8v av = *(const short8v*)(fvt + arow + m0 + lq * 8);
#pragma unroll
      for (int j = 0; j < 4; ++j) {
        size_t brow = (size_t)(hb * 64 + j * 16 + fr) * 1024 + m0 + lq * 8;
        short8v bp = *(const short8v*)(fkt + brow);
        short8v bh = *(const short8v*)(fkh + brow);
        apl[j] = __builtin_amdgcn_mfma_f32_16x16x32_bf16(av, bp, apl[j], 0, 0, 0);
        aht[j] = __builtin_amdgcn_mfma_f32_16x16x32_bf16(av, bh, aht[j], 0, 0, 0);
      }
    }
#pragma unroll
    for (int j = 0; j < 4; ++j)
#pragma unroll
      for (int rr = 0; rr < 4; ++rr) {
        int dv = wv * 16 + lq * 4 + rr, dk = j * 16 + fr;
        A_T[(size_t)hb * 8192 + dv * 64 + dk] = __float2bfloat16(apl[j][rr]);
        A_T[(size_t)hb * 8192 + 4096 + dv * 64 + dk] = __float2bfloat16(aht[j][rr]);
      }
  } else if (bid < 64) {
    int hb = bid - 32;
    float* kmL = sh; float* kvL = sh + 1024; float* red = sh + 2048;
    for (int i = tid; i < 1024; i += 256) {
      kmL[i] = mn[32768 + hb * 1024 + i];
      kvL[i] = vr[32768 + hb * 1024 + i];
    }
    __syncthreads();
    int dv = tid >> 2, seg = tid & 3;
    float am = 0.f, av = 0.f;
    size_t rowb = (size_t)(hb * 64 + dv) * 1024 + seg * 256;
    for (int i = 0; i < 256; i += 8) {
      short8v vv = *(const short8v*)(fvt + rowb + i);
#pragma unroll
      for (int e = 0; e < 8; ++e) {
        float f = b2f(vv[e]);
        am += kmL[seg * 256 + i + e] * f;
        av += kvL[seg * 256 + i + e] * f;
      }
    }
    red[dv * 4 + seg] = am;
    red[256 + dv * 4 + seg] = av;
    __syncthreads();
    if (tid < 64) {
      kvm[hb * 64 + tid] = red[tid * 4] + red[tid * 4 + 1] + red[tid * 4 + 2] + red[tid * 4 + 3];
      kvv[hb * 64 + tid] = red[256 + tid * 4] + red[256 + tid * 4 + 1] +
                           red[256 + tid * 4 + 2] + red[256 + tid * 4 + 3];
    }
  } else {
    float* fqv = sh; float* fkv = sh + 512;
    for (int c = tid; c < 512; c += 256) {
      float sq = 0.f, sk = 0.f;
      for (int p = 0; p < 64; ++p) {
        sq += gp[(size_t)p * 512 + c];
        sk += gp[(size_t)(64 + p) * 512 + c];
      }
      fqv[c] = sq * (1.f / 4096.f);
      fkv[c] = sk * (1.f / 4096.f);
    }
    __syncthreads();
#pragma unroll
    for (int hh = 0; hh < 2; ++hh) {
      int h = hh * 4 + wv, j = l;
      float pre = b1[j];
      for (int i = 0; i < 64; ++i) pre += fqv[h * 64 + i] * W1[j * 128 + i];
      for (int i = 0; i < 64; ++i) pre += fkv[h * 64 + i] * W1[j * 128 + 64 + i];
      float s = wred_sum(pre);
      float ss = wred_sum(pre * pre);
      float mean = s * (1.f / 64.f);
      float var = ss * (1.f / 64.f) - mean * mean;
      float hdn = (pre - mean) * rsqrtf(var + LN_EPS) * lg[j] + lb[j];
      hdn = fmaxf(hdn, 0.f);
      float l0 = wred_sum(hdn * W2[0 * 64 + j]) + b2[0];
      float l1 = wred_sum(hdn * W2[1 * 64 + j]) + b2[1];
      float l2 = wred_sum(hdn * W2[2 * 64 + j]) + b2[2];
      float mx = fmaxf(l0, fmaxf(l1, l2));
      float e0 = __expf(l0 - mx), e1 = __expf(l1 - mx), e2 = __expf(l2 - mx);
      float inv = 1.f / (e0 + e1 + e2);
      if (j == 0) {
        wts[h * 3 + 0] = e0 * inv;
        wts[h * 3 + 1] = e1 * inv;
        wts[h * 3 + 2] = e2 * inv;
      }
    }
  }
}

// ---------------- apply: out = w0*qrn*(Q@Ahat^T) + f1*(Q@Apl^T) + rank1 ------
__global__ __launch_bounds__(256) void apply_kernel(
    const bf16* __restrict__ f_q, const bf16* __restrict__ A_T,
    const float* __restrict__ rn, const float* __restrict__ mn,
    const float* __restrict__ vr, const float* __restrict__ wts,
    const float* __restrict__ kvm, const float* __restrict__ kvv,
    bf16* __restrict__ attnb) {
  __shared__ bf16 Qs[64 * 72];
  __shared__ bf16 Ap[64 * 72];
  __shared__ bf16 Ah[64 * 72];
  __shared__ float qrnL[64], qmnL[64], qvrL[64], kvmL[64], kvvL[64];
  int qt = blockIdx.x, hbid = blockIdx.y;
  int h = hbid >> 2, b = hbid & 3;
  int tid = threadIdx.x;
  int wv = tid >> 6, l = tid & 63, fr = l & 15, lq = l >> 4;
  {
    int row = tid >> 2, qq = (tid & 3) * 16;
    const bf16* qsrc = f_q + (size_t)(b * 1024 + qt * 64 + row) * 512 + h * 64 + qq;
    *(short8v*)&Qs[row * 72 + qq] = *(const short8v*)qsrc;
    *(short8v*)&Qs[row * 72 + qq + 8] = *(const short8v*)(qsrc + 8);
    const bf16* asrc = A_T + (size_t)hbid * 8192 + row * 64 + qq;
    *(short8v*)&Ap[row * 72 + qq] = *(const short8v*)asrc;
    *(short8v*)&Ap[row * 72 + qq + 8] = *(const short8v*)(asrc + 8);
    *(short8v*)&Ah[row * 72 + qq] = *(const short8v*)(asrc + 4096);
    *(short8v*)&Ah[row * 72 + qq + 8] = *(const short8v*)(asrc + 4096 + 8);
  }
  if (tid < 64) {
    qrnL[tid] = rn[(size_t)hbid * 1024 + qt * 64 + tid];
    qmnL[tid] = mn[(size_t)hbid * 1024 + qt * 64 + tid];
    qvrL[tid] = vr[(size_t)hbid * 1024 + qt * 64 + tid];
    kvmL[tid] = kvm[hbid * 64 + tid];
    kvvL[tid] = kvv[hbid * 64 + tid];
  }
  __syncthreads();
  f32x4 ap_[4], ah_[4];
#pragma unroll
  for (int j = 0; j < 4; ++j)
#pragma unroll
    for (int e = 0; e < 4; ++e) { ap_[j][e] = 0.f; ah_[j][e] = 0.f; }
#pragma unroll
  for (int kk = 0; kk < 64; kk += 32) {
    short8v aq = *(const short8v*)&Qs[(wv * 16 + fr) * 72 + kk + lq * 8];
#pragma unroll
    for (int j = 0; j < 4; ++j) {
      short8v bp = *(const short8v*)&Ap[(j * 16 + fr) * 72 + kk + lq * 8];
      short8v bh = *(const short8v*)&Ah[(j * 16 + fr) * 72 + kk + lq * 8];
      ap_[j] = __builtin_amdgcn_mfma_f32_16x16x32_bf16(aq, bp, ap_[j], 0, 0, 0);
      ah_[j] = __builtin_amdgcn_mfma_f32_16x16x32_bf16(aq, bh, ah_[j], 0, 0, 0);
    }
  }
  float w0 = wts[h * 3 + 0], w1 = wts[h * 3 + 1], w2 = wts[h * 3 + 2];
  float f1 = w1 * (1.f / 64.f), w264 = w2 * (1.f / 64.f);
#pragma unroll
  for (int j = 0; j < 4; ++j) {
    int dv = j * 16 + fr;
    float km = kvmL[dv], kv2 = kvvL[dv];
#pragma unroll
    for (int rr = 0; rr < 4; ++rr) {
      int n = wv * 16 + lq * 4 + rr;
      float o = w0 * qrnL[n] * ah_[j][rr] + f1 * ap_[j][rr]
              - w1 * qmnL[n] * km + w264 * qvrL[n] * kv2;
      attnb[(size_t)(b * 1024 + qt * 64 + n) * 512 + h * 64 + dv] = __float2bfloat16(o);
    }
  }
}

extern "C" void kernel_launch(void* const* d_in, const int* in_sizes, int n_in,
                              void* d_out, int out_size, void* d_ws, size_t ws_size,
                              hipStream_t stream) {
  const float* q     = (const float*)d_in[0];
  const float* k     = (const float*)d_in[1];
  const float* v     = (const float*)d_in[2];
  const float* ln_g  = (const float*)d_in[3];
  const float* ln_b  = (const float*)d_in[4];
  const float* W_in  = (const float*)d_in[5];
  const float* W_out = (const float*)d_in[6];
  const float* b_out = (const float*)d_in[7];
  const float* wp_W1 = (const float*)d_in[8];
  const float* wp_b1 = (const float*)d_in[9];
  const float* wp_lg = (const float*)d_in[10];
  const float* wp_lb = (const float*)d_in[11];
  const float* wp_W2 = (const float*)d_in[12];
  const float* wp_b2 = (const float*)d_in[13];
  float* out = (float*)d_out;

  char* w8 = (char*)d_ws;
  bf16* abf   = (bf16*)(w8);                              // 12 MB (ln'd q,k,v)
  bf16* f_q   = (bf16*)(w8 + (12u << 20));                // 4 MB
  bf16* fkt   = (bf16*)(w8 + (16u << 20));                // 4 MB
  bf16* fkh   = (bf16*)(w8 + (20u << 20));                // 4 MB
  bf16* fvt   = (bf16*)(w8 + (24u << 20));                // 4 MB
  bf16* attnb = (bf16*)(w8 + (28u << 20));                // 4 MB
  bf16* A_T   = (bf16*)(w8 + (32u << 20));                // 512 KB
  bf16* Wib   = (bf16*)(w8 + (32u << 20) + (512u << 10)); // 512 KB
  bf16* Wob   = (bf16*)(w8 + (33u << 20));                // 512 KB
  float* fb   = (float*)(w8 + (33u << 20) + (512u << 10));
  float* rn  = fb;            // 32768
  float* mn  = fb + 32768;    // 65536 (q, k)
  float* vr  = fb + 98304;    // 65536
  float* gp  = fb + 163840;   // 65536 ([2*64][512])
  float* kvm = fb + 229376;   // 2048
  float* kvv = fb + 231424;   // 2048
  float* wts = fb + 233472;   // 24

  lncvt_kernel<<<3200, 256, 0, stream>>>(q, k, v, ln_g, ln_b, W_in, W_out,
                                         abf, Wib, Wob);
  mm_kernel<0><<<dim3(4, 192), 256, 0, stream>>>(
      abf, Wib, nullptr, f_q, fkt, fkh, fvt, rn, mn, vr, gp, nullptr);
  aux_kernel<<<65, 256, 0, stream>>>(
      fvt, fkt, fkh, mn, vr, gp, wp_W1, wp_b1, wp_lg, wp_lb, wp_W2, wp_b2,
      A_T, kvm, kvv, wts);
  apply_kernel<<<dim3(16, 32), 256, 0, stream>>>(
      f_q, A_T, rn, mn, vr, wts, kvm, kvv, attnb);
  mm_kernel<1><<<dim3(4, 64), 256, 0, stream>>>(
      attnb, Wob, b_out, nullptr, nullptr, nullptr, nullptr,
      nullptr, nullptr, nullptr, nullptr, out);
}